// Round 8
// baseline (106.526 us; speedup 1.0000x reference)
//
#include <hip/hip_runtime.h>
#include <hip/hip_bf16.h>
#include <math.h>

#define B_ 8
#define L_ 4096
#define C_ 512
#define LO_ 2048   // L/2
#define SLOTS 8
#define LM_ 2056   // SLOTS + LO_

typedef __attribute__((ext_vector_type(8))) short bf16x8;
typedef __attribute__((ext_vector_type(4))) float f32x4;
typedef unsigned short ushort_t;

__device__ __forceinline__ float waveReduceSum(float v){
  #pragma unroll
  for (int off = 32; off; off >>= 1) v += __shfl_xor(v, off);
  return v;
}
__device__ __forceinline__ unsigned short f2bf(float f){
  unsigned u = __float_as_uint(f);
  u += 0x7fffu + ((u >> 16) & 1u);   // RNE
  return (unsigned short)(u >> 16);
}
__device__ __forceinline__ float bf2f(unsigned short b){
  return __uint_as_float(((unsigned)b) << 16);
}
__device__ __forceinline__ float dot4(float4 a, float4 b){
  return a.x*b.x + a.y*b.y + a.z*b.z + a.w*b.w;
}
__device__ __forceinline__ float sum4(float4 a){ return a.x + a.y + a.z + a.w; }

#define GLOAD_LDS16(g, l) __builtin_amdgcn_global_load_lds( \
    (__attribute__((address_space(1))) void*)(g), \
    (__attribute__((address_space(3))) void*)(l), 16, 0, 0)

// ---------------- fused: [pw cast] + LN1 + carrier score + depthwise conv + GELU + pooled ----
// 2048 blocks x 512 threads; block = 8 outputs (17 source rows).
// Phase 2 uses g1-folded conv weights: h = sum_k tmp_k*(g*w_k) + (b*sum(w)+db), tmp = x*rs - m*rs.
__global__ __launch_bounds__(512) void k_conv(
    const float* __restrict__ lat, const float* __restrict__ g1, const float* __restrict__ b1,
    const float* __restrict__ dw, const float* __restrict__ db,
    const float* __restrict__ cw, const float* __restrict__ cbp,
    const float* __restrict__ pw, ushort_t* __restrict__ pwb,
    ushort_t* __restrict__ hbuf, ushort_t* __restrict__ pooled, float* __restrict__ scores)
{
  __shared__ float rows[17][C_];   // 34 KB
  __shared__ float stat[17][2];    // mrs (m*rstd), rstd
  __shared__ float sd_[17];
  __shared__ float sc_[2];         // sgc, sbc
  int blk = blockIdx.x;            // b * 256 + chunk
  int b = blk >> 8;
  int chunk = blk & 255;
  int t0 = chunk * 8;
  int tid = threadIdx.x;
  int wv = tid >> 6, lane = tid & 63;
  int lbase = 16 * chunk - 1;      // in-batch row of r=0 (may be -1)

  if (blk < 256){
    int i = blk * 1024 + tid * 2;
    float2 v = *(const float2*)(pw + i);
    ushort2 o; o.x = f2bf(v.x); o.y = f2bf(v.y);
    *(ushort2*)(pwb + i) = o;
  }

  int c4 = lane * 4;
  float4 glo = *(const float4*)(g1 + c4);
  float4 ghi = *(const float4*)(g1 + 256 + c4);
  float4 wlo = *(const float4*)(cw + c4);
  float4 whi = *(const float4*)(cw + 256 + c4);
  float4 gclo, gchi;
  gclo.x = glo.x*wlo.x; gclo.y = glo.y*wlo.y; gclo.z = glo.z*wlo.z; gclo.w = glo.w*wlo.w;
  gchi.x = ghi.x*whi.x; gchi.y = ghi.y*whi.y; gchi.z = ghi.z*whi.z; gchi.w = ghi.w*whi.w;

  if (wv == 7){
    float4 blo = *(const float4*)(b1 + c4);
    float4 bhi = *(const float4*)(b1 + 256 + c4);
    float sgc = waveReduceSum(sum4(gclo) + sum4(gchi));
    float sbc = waveReduceSum(dot4(blo, wlo) + dot4(bhi, whi));
    if (lane == 0){ sc_[0] = sgc; sc_[1] = sbc; }
  }

  for (int r = wv; r < 17; r += 8){
    int l = lbase + r;
    float4 v0, v1;
    if (l >= 0){
      const float* xp = lat + ((size_t)(b * L_ + l)) * C_;
      v0 = *(const float4*)(xp + c4);
      v1 = *(const float4*)(xp + 256 + c4);
    } else {
      v0.x=0.f; v0.y=0.f; v0.z=0.f; v0.w=0.f;
      v1 = v0;
    }
    *(float4*)&rows[r][c4] = v0;
    *(float4*)&rows[r][256 + c4] = v1;
    float s1 = waveReduceSum(sum4(v0) + sum4(v1));
    float s2 = waveReduceSum(dot4(v0, v0) + dot4(v1, v1));
    float sd = waveReduceSum(dot4(v0, gclo) + dot4(v1, gchi));
    if (lane == 0){
      float m = s1 * (1.f / C_);
      float var = s2 * (1.f / C_) - m * m;
      float rstd = rsqrtf(var + 1e-5f);
      stat[r][0] = m * rstd;
      stat[r][1] = rstd;
      sd_[r] = sd;
    }
  }
  __syncthreads();

  if (tid >= 1 && tid <= 16){
    int r = tid;
    // (sd - m*sgc)*rstd = sd*rstd - mrs*sgc
    float sc = sd_[r] * stat[r][1] - stat[r][0] * sc_[0] + sc_[1] + cbp[0];
    scores[b * L_ + lbase + r] = sc;
  }

  // phase 2: thread = (th, cq): th -> outputs {2th, 2th+1}; 5 rows 4th..4th+4
  int th = tid >> 7;
  int cq = (tid & 127) * 4;
  float4 gq = *(const float4*)(g1 + cq);
  float4 bq = *(const float4*)(b1 + cq);
  float4 dbq = *(const float4*)(db + cq);
  float4 w0 = *(const float4*)(dw + cq*3);
  float4 w1 = *(const float4*)(dw + cq*3 + 4);
  float4 w2 = *(const float4*)(dw + cq*3 + 8);
  // per-channel kernel taps
  float wk[4][3] = {{w0.x, w0.y, w0.z}, {w0.w, w1.x, w1.y},
                    {w1.z, w1.w, w2.x}, {w2.y, w2.z, w2.w}};
  float gk[4] = {gq.x, gq.y, gq.z, gq.w};
  float bk[4] = {bq.x, bq.y, bq.z, bq.w};
  float dbk[4] = {dbq.x, dbq.y, dbq.z, dbq.w};
  float gwk[4][3], bck[4], bw0k[4];
  #pragma unroll
  for (int k = 0; k < 4; k++){
    gwk[k][0] = gk[k]*wk[k][0]; gwk[k][1] = gk[k]*wk[k][1]; gwk[k][2] = gk[k]*wk[k][2];
    bck[k] = bk[k]*(wk[k][0]+wk[k][1]+wk[k][2]) + dbk[k];
    bw0k[k] = bk[k]*wk[k][0];
  }
  // load 5 rows, pre-scale
  int rb = 4*th;
  float4 xv[5]; float tmp[5][4];
  #pragma unroll
  for (int r5 = 0; r5 < 5; r5++){
    xv[r5] = *(const float4*)&rows[rb + r5][cq];
    float mrs = stat[rb + r5][0], rs = stat[rb + r5][1];
    tmp[r5][0] = xv[r5].x * rs - mrs;
    tmp[r5][1] = xv[r5].y * rs - mrs;
    tmp[r5][2] = xv[r5].z * rs - mrs;
    tmp[r5][3] = xv[r5].w * rs - mrs;
  }
  #pragma unroll
  for (int i = 0; i < 2; i++){
    int t = th * 2 + i;
    int rl = 2*i, rm = 2*i+1, rrg = 2*i+2;   // local in 5-row window
    bool zpad = (chunk == 0 && t == 0);
    float xm4[4] = {xv[rm].x, xv[rm].y, xv[rm].z, xv[rm].w};
    float xr4[4] = {xv[rrg].x, xv[rrg].y, xv[rrg].z, xv[rrg].w};
    ushort4 hv, pv;
    unsigned short* hp = (unsigned short*)&hv;
    unsigned short* pp = (unsigned short*)&pv;
    #pragma unroll
    for (int k = 0; k < 4; k++){
      float tl = zpad ? 0.f : tmp[rl][k];
      float bc = zpad ? (bck[k] - bw0k[k]) : bck[k];
      float hh = tl*gwk[k][0] + tmp[rm][k]*gwk[k][1] + tmp[rrg][k]*gwk[k][2] + bc;
      float ge = 0.5f * hh * (1.f + erff(hh * 0.70710678118654752440f));
      hp[k] = f2bf(ge);
      pp[k] = f2bf(0.5f * (xm4[k] + xr4[k]));
    }
    size_t oidx = ((size_t)(b * LO_ + t0 + t)) * C_ + cq;
    *(ushort4*)(hbuf + oidx) = hv;
    *(ushort4*)(pooled + oidx) = pv;
  }
}

// ============ fused GEMM + epilogue v2 ============
// 512 blocks x 256 threads (4 waves). Block = 32 reduced rows x all 512 cols -> 2 blocks/CU.
// Wave w -> cols [w*128, w*128+128): acc 2x8 frags. red flushed to LDS (union), row-waves finish.
__global__ __launch_bounds__(256) void k_gemmepi(
    const ushort_t* __restrict__ Ah, const ushort_t* __restrict__ Bw,
    const float* __restrict__ pb, const ushort_t* __restrict__ pooled,
    const float* __restrict__ gw, const float* __restrict__ gbp,
    const float* __restrict__ g2, const float* __restrict__ b2,
    float* __restrict__ out, float* __restrict__ gateout)
{
  __shared__ union UU {
    struct { ushort_t As[2][32*32]; ushort_t Bs[2][512*32]; } g;  // 4KB + 64KB = 68KB
    float red[32*516];                                            // 66KB (reused after GEMM)
  } u;

  int blk = blockIdx.x;          // 0..511, 32 rows each (64 blocks per batch, no crossing)
  int R0 = blk * 32;
  int tid = threadIdx.x;
  int w = tid >> 6, lane = tid & 63;
  const ushort_t* Ap = Ah + (size_t)R0 * C_;

#define STAGE(buf, kt) { \
    int kk = (kt) * 32; \
    if (w < 2){ \
      GLOAD_LDS16(Ap + (size_t)(w*16 + (lane>>2))*C_ + kk + (lane&3)*8, &u.g.As[buf][w*512]); \
    } \
    _Pragma("unroll") \
    for (int uu = 0; uu < 8; uu++){ \
      int unit = w*8 + uu; \
      GLOAD_LDS16(Bw + (size_t)(unit*16 + (lane>>2))*C_ + kk + (lane&3)*8, &u.g.Bs[buf][unit*512]); \
    } }

  int fr = lane & 15, kq = (lane >> 4) * 8;
  int wc = w * 128;
  f32x4 acc[2][8];
  #pragma unroll
  for (int m = 0; m < 2; m++)
    #pragma unroll
    for (int n = 0; n < 8; n++)
      acc[m][n] = (f32x4){0.f, 0.f, 0.f, 0.f};

  STAGE(0, 0);
  __syncthreads();
  for (int kt = 0; kt < 16; kt++){
    int cur = kt & 1;
    if (kt < 15){ STAGE(cur ^ 1, kt + 1); }
    bf16x8 af[2], bfr[8];
    #pragma unroll
    for (int m = 0; m < 2; m++)
      af[m] = *(const bf16x8*)&u.g.As[cur][(m*16 + fr)*32 + kq];
    #pragma unroll
    for (int n = 0; n < 8; n++)
      bfr[n] = *(const bf16x8*)&u.g.Bs[cur][(wc + n*16 + fr)*32 + kq];
    #pragma unroll
    for (int m = 0; m < 2; m++)
      #pragma unroll
      for (int n = 0; n < 8; n++)
        acc[m][n] = __builtin_amdgcn_mfma_f32_16x16x32_bf16(af[m], bfr[n], acc[m][n], 0, 0, 0);
    __syncthreads();   // drains staging (vmcnt0) + protects buffer reuse
  }
#undef STAGE

  // bias add (C/D layout: col = lane&15, row = (lane>>4)*4 + j)
  int cq = fr, rq = (lane >> 4) * 4;
  #pragma unroll
  for (int n = 0; n < 8; n++){
    float pbv = pb[wc + n*16 + cq];
    #pragma unroll
    for (int m = 0; m < 2; m++)
      #pragma unroll
      for (int j = 0; j < 4; j++)
        acc[m][n][j] += pbv;
  }

  // flush acc -> red LDS (union over staging buffers)
  __syncthreads();
  #pragma unroll
  for (int m = 0; m < 2; m++)
    #pragma unroll
    for (int n = 0; n < 8; n++)
      #pragma unroll
      for (int j = 0; j < 4; j++)
        u.red[(m*16 + rq + j)*516 + wc + n*16 + cq] = acc[m][n][j];
  __syncthreads();

  // epilogue: wave w -> rows w*8 .. w*8+7
  int c4 = lane * 4;
  float4 gw1lo = *(const float4*)(gw + c4);
  float4 gw1hi = *(const float4*)(gw + 256 + c4);
  float4 gw2lo = *(const float4*)(gw + C_ + c4);
  float4 gw2hi = *(const float4*)(gw + C_ + 256 + c4);
  float4 g2lo = *(const float4*)(g2 + c4);
  float4 g2hi = *(const float4*)(g2 + 256 + c4);
  float4 b2lo = *(const float4*)(b2 + c4);
  float4 b2hi = *(const float4*)(b2 + 256 + c4);
  float gb0 = gbp[0];
  #pragma unroll
  for (int rr = 0; rr < 8; rr++){
    int rloc = w*8 + rr;
    int grow = R0 + rloc;                  // global reduced row (= b*LO + l)
    const float* redrow = &u.red[rloc * 516];
    float4 rlo = *(const float4*)&redrow[c4];
    float4 rhi = *(const float4*)&redrow[256 + c4];
    const ushort_t* prow = pooled + (size_t)grow * C_;
    ushort4 p4l = *(const ushort4*)(prow + c4);
    ushort4 p4h = *(const ushort4*)(prow + 256 + c4);
    float4 plov, phiv;
    plov.x = bf2f(p4l.x); plov.y = bf2f(p4l.y); plov.z = bf2f(p4l.z); plov.w = bf2f(p4l.w);
    phiv.x = bf2f(p4h.x); phiv.y = bf2f(p4h.y); phiv.z = bf2f(p4h.z); phiv.w = bf2f(p4h.w);
    float rdot = waveReduceSum(dot4(rlo, gw1lo) + dot4(rhi, gw1hi));
    float pdot = waveReduceSum(dot4(plov, gw2lo) + dot4(phiv, gw2hi));
    float gate = 0.5f + 0.5f / (1.f + expf(-(rdot + pdot + gb0)));
    float4 mlo, mhi;
    mlo.x = plov.x + gate * (rlo.x - plov.x);
    mlo.y = plov.y + gate * (rlo.y - plov.y);
    mlo.z = plov.z + gate * (rlo.z - plov.z);
    mlo.w = plov.w + gate * (rlo.w - plov.w);
    mhi.x = phiv.x + gate * (rhi.x - phiv.x);
    mhi.y = phiv.y + gate * (rhi.y - phiv.y);
    mhi.z = phiv.z + gate * (rhi.z - phiv.z);
    mhi.w = phiv.w + gate * (rhi.w - phiv.w);
    float s1 = waveReduceSum(sum4(mlo) + sum4(mhi));
    float s2 = waveReduceSum(dot4(mlo, mlo) + dot4(mhi, mhi));
    float mean = s1 * (1.f / C_);
    float rstd = rsqrtf(s2 * (1.f / C_) - mean * mean + 1e-5f);
    int b = grow >> 11, l = grow & (LO_ - 1);
    float* op = out + ((size_t)(b * LM_ + SLOTS + l)) * C_;
    float4 olo, ohi;
    olo.x = (mlo.x - mean) * rstd * g2lo.x + b2lo.x;
    olo.y = (mlo.y - mean) * rstd * g2lo.y + b2lo.y;
    olo.z = (mlo.z - mean) * rstd * g2lo.z + b2lo.z;
    olo.w = (mlo.w - mean) * rstd * g2lo.w + b2lo.w;
    ohi.x = (mhi.x - mean) * rstd * g2hi.x + b2hi.x;
    ohi.y = (mhi.y - mean) * rstd * g2hi.y + b2hi.y;
    ohi.z = (mhi.z - mean) * rstd * g2hi.z + b2hi.z;
    ohi.w = (mhi.w - mean) * rstd * g2hi.w + b2hi.w;
    *(float4*)(op + c4) = olo;
    *(float4*)(op + 256 + c4) = ohi;
    if (lane == 0) gateout[grow] = gate;
  }
}

// ---------------- top-8 (block per batch) + carrier gather + LN2 ----------------
__global__ __launch_bounds__(1024) void k_topk(
    const float* __restrict__ scores, const float* __restrict__ lat,
    const float* __restrict__ g2, const float* __restrict__ b2, float* __restrict__ out)
{
  __shared__ float sv[L_];
  __shared__ float rv_[16];
  __shared__ int   ri_[16];
  __shared__ int   chosen[SLOTS];
  int b = blockIdx.x, tid = threadIdx.x;
  #pragma unroll
  for (int j = 0; j < 4; j++) sv[tid + j * 1024] = scores[b * L_ + tid + j * 1024];
  __syncthreads();
  int wv = tid >> 6, lane = tid & 63;
  for (int it = 0; it < SLOTS; it++){
    float best = -INFINITY; int bi = L_;
    #pragma unroll
    for (int j = 0; j < 4; j++){
      int i = tid + j * 1024;
      float v = sv[i];
      if (v > best || (v == best && i < bi)){ best = v; bi = i; }
    }
    #pragma unroll
    for (int off = 32; off; off >>= 1){
      float ov = __shfl_xor(best, off); int oi = __shfl_xor(bi, off);
      if (ov > best || (ov == best && oi < bi)){ best = ov; bi = oi; }
    }
    if (lane == 0){ rv_[wv] = best; ri_[wv] = bi; }
    __syncthreads();
    if (tid == 0){
      for (int w2 = 1; w2 < 16; w2++){
        if (rv_[w2] > best || (rv_[w2] == best && ri_[w2] < bi)){ best = rv_[w2]; bi = ri_[w2]; }
      }
      chosen[it] = bi;
      sv[bi] = -INFINITY;
    }
    __syncthreads();
  }
  if (tid == 0){
    for (int i = 0; i < SLOTS; i++)
      for (int j = i + 1; j < SLOTS; j++)
        if (chosen[j] < chosen[i]){ int t = chosen[i]; chosen[i] = chosen[j]; chosen[j] = t; }
  }
  __syncthreads();
  if (wv < SLOTS){
    int s = wv;
    int l = chosen[s];
    const float* x = lat + ((size_t)(b * L_ + l)) * C_;
    float xs[8];
    float s1 = 0.f, s2 = 0.f;
    #pragma unroll
    for (int i = 0; i < 2; i++){
      float4 vv = *(const float4*)(x + i * 256 + lane * 4);
      xs[i*4+0] = vv.x; xs[i*4+1] = vv.y; xs[i*4+2] = vv.z; xs[i*4+3] = vv.w;
      s1 += vv.x + vv.y + vv.z + vv.w;
      s2 += vv.x*vv.x + vv.y*vv.y + vv.z*vv.z + vv.w*vv.w;
    }
    s1 = waveReduceSum(s1); s2 = waveReduceSum(s2);
    float m = s1 * (1.f / C_);
    float rstd = rsqrtf(s2 * (1.f / C_) - m * m + 1e-5f);
    float* o = out + ((size_t)(b * LM_ + s)) * C_;
    #pragma unroll
    for (int i = 0; i < 2; i++){
      int cc = i * 256 + lane * 4;
      float4 gv = *(const float4*)(g2 + cc);
      float4 bv = *(const float4*)(b2 + cc);
      float4 ov;
      ov.x = (xs[i*4+0] - m) * rstd * gv.x + bv.x;
      ov.y = (xs[i*4+1] - m) * rstd * gv.y + bv.y;
      ov.z = (xs[i*4+2] - m) * rstd * gv.z + bv.z;
      ov.w = (xs[i*4+3] - m) * rstd * gv.w + bv.w;
      *(float4*)(o + cc) = ov;
    }
  }
}

extern "C" void kernel_launch(void* const* d_in, const int* in_sizes, int n_in,
                              void* d_out, int out_size, void* d_ws, size_t ws_size,
                              hipStream_t stream)
{
  const float* lat = (const float*)d_in[0];
  const float* g1  = (const float*)d_in[1];
  const float* b1  = (const float*)d_in[2];
  const float* dw  = (const float*)d_in[3];
  const float* db  = (const float*)d_in[4];
  const float* pw  = (const float*)d_in[5];
  const float* pb  = (const float*)d_in[6];
  const float* gw  = (const float*)d_in[7];
  const float* gb  = (const float*)d_in[8];
  const float* cw  = (const float*)d_in[9];
  const float* cb  = (const float*)d_in[10];
  const float* g2  = (const float*)d_in[11];
  const float* b2  = (const float*)d_in[12];

  float* out = (float*)d_out;
  float* gateout = out + (size_t)B_ * LM_ * C_;

  const size_t NHL = (size_t)B_ * LO_ * C_;   // 8388608
  ushort_t* hbuf   = (ushort_t*)d_ws;
  ushort_t* pooled = hbuf + NHL;
  ushort_t* pwb    = pooled + NHL;
  float*    scores = (float*)(pwb + (size_t)C_ * C_);

  hipLaunchKernelGGL(k_conv,    dim3(B_ * LO_ / 8), dim3(512), 0, stream,
                     lat, g1, b1, dw, db, cw, cb, pw, pwb, hbuf, pooled, scores);
  hipLaunchKernelGGL(k_topk,    dim3(B_), dim3(1024), 0, stream, scores, lat, g2, b2, out);
  hipLaunchKernelGGL(k_gemmepi, dim3(B_ * LO_ / 32), dim3(256), 0, stream,
                     hbuf, pwb, pb, pooled, gw, gb, g2, b2, out, gateout);
}

// Round 11
// 103.465 us; speedup vs baseline: 1.0296x; 1.0296x over previous
//
#include <hip/hip_runtime.h>
#include <hip/hip_bf16.h>
#include <hip/hip_fp16.h>
#include <math.h>

#define B_ 8
#define L_ 4096
#define C_ 512
#define LO_ 2048   // L/2
#define SLOTS 8
#define LM_ 2056   // SLOTS + LO_

typedef _Float16 f16x8 __attribute__((ext_vector_type(8)));
typedef __attribute__((ext_vector_type(4))) float f32x4;
typedef unsigned short ushort_t;

__device__ __forceinline__ float waveReduceSum(float v){
  #pragma unroll
  for (int off = 32; off; off >>= 1) v += __shfl_xor(v, off);
  return v;
}
__device__ __forceinline__ unsigned short f2h(float f){
  __half h = __float2half(f);          // RNE
  return *reinterpret_cast<unsigned short*>(&h);
}
__device__ __forceinline__ float dot4(float4 a, float4 b){
  return a.x*b.x + a.y*b.y + a.z*b.z + a.w*b.w;
}
__device__ __forceinline__ float sum4(float4 a){ return a.x + a.y + a.z + a.w; }

#define GLOAD_LDS16(g, l) __builtin_amdgcn_global_load_lds( \
    (__attribute__((address_space(1))) void*)(g), \
    (__attribute__((address_space(3))) void*)(l), 16, 0, 0)

// ---------------- fused: [pw cast] + LN1 + carrier score + depthwise conv + GELU + pooled ----
// R7-validated numerics; h -> fp16, pooled -> fp32. 2048 blocks x 512 threads; 8 outputs/block.
__global__ __launch_bounds__(512) void k_conv(
    const float* __restrict__ lat, const float* __restrict__ g1, const float* __restrict__ b1,
    const float* __restrict__ dw, const float* __restrict__ db,
    const float* __restrict__ cw, const float* __restrict__ cbp,
    const float* __restrict__ pw, ushort_t* __restrict__ pwh,
    ushort_t* __restrict__ hbuf, float* __restrict__ pooled, float* __restrict__ scores)
{
  __shared__ float rows[17][C_];   // 34 KB
  __shared__ float stat[17][3];    // m, rstd, sd
  __shared__ float sc_[2];         // sgc, sbc
  int blk = blockIdx.x;            // b * 256 + chunk
  int b = blk >> 8;
  int chunk = blk & 255;
  int t0 = chunk * 8;
  int tid = threadIdx.x;
  int wv = tid >> 6, lane = tid & 63;
  int lbase = 16 * chunk - 1;      // in-batch row of r=0 (may be -1)

  if (blk < 256){
    int i = blk * 1024 + tid * 2;
    float2 v = *(const float2*)(pw + i);
    ushort2 o; o.x = f2h(v.x); o.y = f2h(v.y);
    *(ushort2*)(pwh + i) = o;
  }

  int c4 = lane * 4;
  float4 glo = *(const float4*)(g1 + c4);
  float4 ghi = *(const float4*)(g1 + 256 + c4);
  float4 wlo = *(const float4*)(cw + c4);
  float4 whi = *(const float4*)(cw + 256 + c4);
  float4 gclo, gchi;
  gclo.x = glo.x*wlo.x; gclo.y = glo.y*wlo.y; gclo.z = glo.z*wlo.z; gclo.w = glo.w*wlo.w;
  gchi.x = ghi.x*whi.x; gchi.y = ghi.y*whi.y; gchi.z = ghi.z*whi.z; gchi.w = ghi.w*whi.w;

  if (wv == 7){
    float4 blo = *(const float4*)(b1 + c4);
    float4 bhi = *(const float4*)(b1 + 256 + c4);
    float sgc = waveReduceSum(sum4(gclo) + sum4(gchi));
    float sbc = waveReduceSum(dot4(blo, wlo) + dot4(bhi, whi));
    if (lane == 0){ sc_[0] = sgc; sc_[1] = sbc; }
  }

  for (int r = wv; r < 17; r += 8){
    int l = lbase + r;
    float4 v0, v1;
    if (l >= 0){
      const float* xp = lat + ((size_t)(b * L_ + l)) * C_;
      v0 = *(const float4*)(xp + c4);
      v1 = *(const float4*)(xp + 256 + c4);
    } else {
      v0.x=0.f; v0.y=0.f; v0.z=0.f; v0.w=0.f;
      v1 = v0;
    }
    *(float4*)&rows[r][c4] = v0;
    *(float4*)&rows[r][256 + c4] = v1;
    float s1 = waveReduceSum(sum4(v0) + sum4(v1));
    float s2 = waveReduceSum(dot4(v0, v0) + dot4(v1, v1));
    float sd = waveReduceSum(dot4(v0, gclo) + dot4(v1, gchi));
    if (lane == 0){
      float m = s1 * (1.f / C_);
      float var = s2 * (1.f / C_) - m * m;
      stat[r][0] = m;
      stat[r][1] = rsqrtf(var + 1e-5f);
      stat[r][2] = sd;
    }
  }
  __syncthreads();

  if (tid >= 1 && tid <= 16){
    int r = tid;
    float sc = (stat[r][2] - stat[r][0] * sc_[0]) * stat[r][1] + sc_[1] + cbp[0];
    scores[b * L_ + lbase + r] = sc;
  }

  int th = tid >> 7;
  int cq = (tid & 127) * 4;
  float4 gq = *(const float4*)(g1 + cq);
  float4 bq = *(const float4*)(b1 + cq);
  float4 dbq = *(const float4*)(db + cq);
  float4 w0 = *(const float4*)(dw + cq*3);
  float4 w1 = *(const float4*)(dw + cq*3 + 4);
  float4 w2 = *(const float4*)(dw + cq*3 + 8);
  float wk[4][3] = {{w0.x, w0.y, w0.z}, {w0.w, w1.x, w1.y},
                    {w1.z, w1.w, w2.x}, {w2.y, w2.z, w2.w}};
  float gk[4] = {gq.x, gq.y, gq.z, gq.w};
  float bk[4] = {bq.x, bq.y, bq.z, bq.w};
  float dbk[4] = {dbq.x, dbq.y, dbq.z, dbq.w};
  #pragma unroll
  for (int i = 0; i < 2; i++){
    int t = th * 2 + i;
    int rl = 2*t, rm = 2*t+1, rrg = 2*t+2;
    float4 xl = *(const float4*)&rows[rl][cq];
    float4 xm = *(const float4*)&rows[rm][cq];
    float4 xrr = *(const float4*)&rows[rrg][cq];
    float ml = stat[rl][0], rlr = stat[rl][1];
    float mm = stat[rm][0], rmr = stat[rm][1];
    float mr2 = stat[rrg][0], rrr = stat[rrg][1];
    bool zpad = (chunk == 0 && t == 0);
    float xlv[4] = {xl.x, xl.y, xl.z, xl.w};
    float xmv[4] = {xm.x, xm.y, xm.z, xm.w};
    float xrv[4] = {xrr.x, xrr.y, xrr.z, xrr.w};
    ushort4 hv;
    float4 pv;
    unsigned short* hp = (unsigned short*)&hv;
    float* pp = (float*)&pv;
    #pragma unroll
    for (int k = 0; k < 4; k++){
      float n0 = zpad ? 0.f : ((xlv[k] - ml) * rlr * gk[k] + bk[k]);
      float n1 = (xmv[k] - mm) * rmr * gk[k] + bk[k];
      float n2 = (xrv[k] - mr2) * rrr * gk[k] + bk[k];
      float hh = n0 * wk[k][0] + n1 * wk[k][1] + n2 * wk[k][2] + dbk[k];
      float ge = 0.5f * hh * (1.f + erff(hh * 0.70710678118654752440f));
      hp[k] = f2h(ge);
      pp[k] = 0.5f * (xmv[k] + xrv[k]);
    }
    size_t oidx = ((size_t)(b * LO_ + t0 + t)) * C_ + cq;
    *(ushort4*)(hbuf + oidx) = hv;
    *(float4*)(pooled + oidx) = pv;
  }
}

// ============ fused GEMM + epilogue — R7-validated structure, fp16 MFMA ============
// 256 blocks x 512 threads (8 waves). Block = 64 reduced rows x all 512 cols.
// Per-kt double-buffered global_load_lds staging; acc flushed 16 rows at a time.
__global__ __launch_bounds__(512, 4) void k_gemmepi(
    const ushort_t* __restrict__ Ah, const ushort_t* __restrict__ Bw,
    const float* __restrict__ pb, const float* __restrict__ pooled,
    const float* __restrict__ gw, const float* __restrict__ gbp,
    const float* __restrict__ g2, const float* __restrict__ b2,
    float* __restrict__ out, float* __restrict__ gateout)
{
  __shared__ union UU {
    struct { ushort_t As[2][64*32]; ushort_t Bs[2][512*32]; } g;  // 8KB + 64KB = 72KB
    float red[16*516];                                            // 33KB chunk (reused after GEMM)
  } u;

  int blk = blockIdx.x;          // 0..255, 64 rows each; 32 blocks per batch (no crossing)
  int R0 = blk * 64;
  int tid = threadIdx.x;
  int w = tid >> 6, lane = tid & 63;
  const ushort_t* Ap = Ah + (size_t)R0 * C_;

#define STAGE(buf, kt) { \
    int kk = (kt) * 32; \
    if (w < 4){ \
      int ar = w*16 + (lane>>2); \
      GLOAD_LDS16(Ap + (size_t)ar*C_ + kk + (lane&3)*8, &u.g.As[buf][w*16*32]); \
    } \
    _Pragma("unroll") \
    for (int uu = 0; uu < 4; uu++){ \
      int unit = w + uu*8; \
      int brow = unit*16 + (lane>>2); \
      GLOAD_LDS16(Bw + (size_t)brow*C_ + kk + (lane&3)*8, &u.g.Bs[buf][unit*16*32]); \
    } }

  int fr = lane & 15, kq = (lane >> 4) * 8;
  int wc = w * 64;
  f32x4 acc[4][4];
  #pragma unroll
  for (int m = 0; m < 4; m++)
    #pragma unroll
    for (int n = 0; n < 4; n++)
      acc[m][n] = (f32x4){0.f, 0.f, 0.f, 0.f};

  STAGE(0, 0);
  __syncthreads();
  for (int kt = 0; kt < 16; kt++){
    int cur = kt & 1;
    if (kt < 15){ STAGE(cur ^ 1, kt + 1); }
    f16x8 af[4], bfr[4];
    #pragma unroll
    for (int m = 0; m < 4; m++)
      af[m] = *(const f16x8*)&u.g.As[cur][(m*16 + fr)*32 + kq];
    #pragma unroll
    for (int n = 0; n < 4; n++)
      bfr[n] = *(const f16x8*)&u.g.Bs[cur][(wc + n*16 + fr)*32 + kq];
    #pragma unroll
    for (int m = 0; m < 4; m++)
      #pragma unroll
      for (int n = 0; n < 4; n++)
        acc[m][n] = __builtin_amdgcn_mfma_f32_16x16x32_f16(af[m], bfr[n], acc[m][n], 0, 0, 0);
    __syncthreads();   // drains staging (vmcnt0) + protects buffer reuse
  }
#undef STAGE

  // bias add (C/D layout: col = lane&15, row = (lane>>4)*4 + j)
  int cq = fr, rq = (lane >> 4) * 4;
  #pragma unroll
  for (int n = 0; n < 4; n++){
    float pbv = pb[wc + n*16 + cq];
    #pragma unroll
    for (int m = 0; m < 4; m++)
      #pragma unroll
      for (int j = 0; j < 4; j++)
        acc[m][n][j] += pbv;
  }

  // epilogue params
  int c4 = lane * 4;
  float4 gw1lo = *(const float4*)(gw + c4);
  float4 gw1hi = *(const float4*)(gw + 256 + c4);
  float4 gw2lo = *(const float4*)(gw + C_ + c4);
  float4 gw2hi = *(const float4*)(gw + C_ + 256 + c4);
  float4 g2lo = *(const float4*)(g2 + c4);
  float4 g2hi = *(const float4*)(g2 + 256 + c4);
  float4 b2lo = *(const float4*)(b2 + c4);
  float4 b2hi = *(const float4*)(b2 + 256 + c4);
  float gb0 = gbp[0];

  // 4 chunks of 16 rows: flush acc[g] -> red LDS, then row-waves finish
  #pragma unroll
  for (int g = 0; g < 4; g++){
    #pragma unroll
    for (int n = 0; n < 4; n++)
      #pragma unroll
      for (int j = 0; j < 4; j++)
        u.red[(rq + j)*516 + wc + n*16 + cq] = acc[g][n][j];
    __syncthreads();
    // wave w -> rows w*2, w*2+1 of this chunk
    #pragma unroll
    for (int rr = 0; rr < 2; rr++){
      int rloc = w*2 + rr;
      int grow = R0 + g*16 + rloc;           // global reduced row (= b*LO + l)
      const float* redrow = &u.red[rloc * 516];
      float4 rlo = *(const float4*)&redrow[c4];
      float4 rhi = *(const float4*)&redrow[256 + c4];
      const float* prow = pooled + (size_t)grow * C_;
      float4 plov = *(const float4*)(prow + c4);
      float4 phiv = *(const float4*)(prow + 256 + c4);
      float rdot = waveReduceSum(dot4(rlo, gw1lo) + dot4(rhi, gw1hi));
      float pdot = waveReduceSum(dot4(plov, gw2lo) + dot4(phiv, gw2hi));
      float gate = 0.5f + 0.5f / (1.f + expf(-(rdot + pdot + gb0)));
      float4 mlo, mhi;
      mlo.x = plov.x + gate * (rlo.x - plov.x);
      mlo.y = plov.y + gate * (rlo.y - plov.y);
      mlo.z = plov.z + gate * (rlo.z - plov.z);
      mlo.w = plov.w + gate * (rlo.w - plov.w);
      mhi.x = phiv.x + gate * (rhi.x - phiv.x);
      mhi.y = phiv.y + gate * (rhi.y - phiv.y);
      mhi.z = phiv.z + gate * (rhi.z - phiv.z);
      mhi.w = phiv.w + gate * (rhi.w - phiv.w);
      float s1 = waveReduceSum(sum4(mlo) + sum4(mhi));
      float s2 = waveReduceSum(dot4(mlo, mlo) + dot4(mhi, mhi));
      float mean = s1 * (1.f / C_);
      float rstd = rsqrtf(s2 * (1.f / C_) - mean * mean + 1e-5f);
      int b = grow >> 11, l = grow & (LO_ - 1);
      float* op = out + ((size_t)(b * LM_ + SLOTS + l)) * C_;
      float4 olo, ohi;
      olo.x = (mlo.x - mean) * rstd * g2lo.x + b2lo.x;
      olo.y = (mlo.y - mean) * rstd * g2lo.y + b2lo.y;
      olo.z = (mlo.z - mean) * rstd * g2lo.z + b2lo.z;
      olo.w = (mlo.w - mean) * rstd * g2lo.w + b2lo.w;
      ohi.x = (mhi.x - mean) * rstd * g2hi.x + b2hi.x;
      ohi.y = (mhi.y - mean) * rstd * g2hi.y + b2hi.y;
      ohi.z = (mhi.z - mean) * rstd * g2hi.z + b2hi.z;
      ohi.w = (mhi.w - mean) * rstd * g2hi.w + b2hi.w;
      *(float4*)(op + c4) = olo;
      *(float4*)(op + 256 + c4) = ohi;
      if (lane == 0) gateout[grow] = gate;
    }
    __syncthreads();   // chunk buffer reuse
  }
}

// ---------------- top-8 (block per batch) + carrier gather + LN2 ----------------
__global__ __launch_bounds__(1024) void k_topk(
    const float* __restrict__ scores, const float* __restrict__ lat,
    const float* __restrict__ g2, const float* __restrict__ b2, float* __restrict__ out)
{
  __shared__ float sv[L_];
  __shared__ float rv_[16];
  __shared__ int   ri_[16];
  __shared__ int   chosen[SLOTS];
  int b = blockIdx.x, tid = threadIdx.x;
  #pragma unroll
  for (int j = 0; j < 4; j++) sv[tid + j * 1024] = scores[b * L_ + tid + j * 1024];
  __syncthreads();
  int wv = tid >> 6, lane = tid & 63;
  for (int it = 0; it < SLOTS; it++){
    float best = -INFINITY; int bi = L_;
    #pragma unroll
    for (int j = 0; j < 4; j++){
      int i = tid + j * 1024;
      float v = sv[i];
      if (v > best || (v == best && i < bi)){ best = v; bi = i; }
    }
    #pragma unroll
    for (int off = 32; off; off >>= 1){
      float ov = __shfl_xor(best, off); int oi = __shfl_xor(bi, off);
      if (ov > best || (ov == best && oi < bi)){ best = ov; bi = oi; }
    }
    if (lane == 0){ rv_[wv] = best; ri_[wv] = bi; }
    __syncthreads();
    if (tid == 0){
      for (int w2 = 1; w2 < 16; w2++){
        if (rv_[w2] > best || (rv_[w2] == best && ri_[w2] < bi)){ best = rv_[w2]; bi = ri_[w2]; }
      }
      chosen[it] = bi;
      sv[bi] = -INFINITY;
    }
    __syncthreads();
  }
  if (tid == 0){
    for (int i = 0; i < SLOTS; i++)
      for (int j = i + 1; j < SLOTS; j++)
        if (chosen[j] < chosen[i]){ int t = chosen[i]; chosen[i] = chosen[j]; chosen[j] = t; }
  }
  __syncthreads();
  if (wv < SLOTS){
    int s = wv;
    int l = chosen[s];
    const float* x = lat + ((size_t)(b * L_ + l)) * C_;
    float xs[8];
    float s1 = 0.f, s2 = 0.f;
    #pragma unroll
    for (int i = 0; i < 2; i++){
      float4 vv = *(const float4*)(x + i * 256 + lane * 4);
      xs[i*4+0] = vv.x; xs[i*4+1] = vv.y; xs[i*4+2] = vv.z; xs[i*4+3] = vv.w;
      s1 += vv.x + vv.y + vv.z + vv.w;
      s2 += vv.x*vv.x + vv.y*vv.y + vv.z*vv.z + vv.w*vv.w;
    }
    s1 = waveReduceSum(s1); s2 = waveReduceSum(s2);
    float m = s1 * (1.f / C_);
    float rstd = rsqrtf(s2 * (1.f / C_) - m * m + 1e-5f);
    float* o = out + ((size_t)(b * LM_ + s)) * C_;
    #pragma unroll
    for (int i = 0; i < 2; i++){
      int cc = i * 256 + lane * 4;
      float4 gv = *(const float4*)(g2 + cc);
      float4 bv = *(const float4*)(b2 + cc);
      float4 ov;
      ov.x = (xs[i*4+0] - m) * rstd * gv.x + bv.x;
      ov.y = (xs[i*4+1] - m) * rstd * gv.y + bv.y;
      ov.z = (xs[i*4+2] - m) * rstd * gv.z + bv.z;
      ov.w = (xs[i*4+3] - m) * rstd * gv.w + bv.w;
      *(float4*)(o + cc) = ov;
    }
  }
}

extern "C" void kernel_launch(void* const* d_in, const int* in_sizes, int n_in,
                              void* d_out, int out_size, void* d_ws, size_t ws_size,
                              hipStream_t stream)
{
  const float* lat = (const float*)d_in[0];
  const float* g1  = (const float*)d_in[1];
  const float* b1  = (const float*)d_in[2];
  const float* dw  = (const float*)d_in[3];
  const float* db  = (const float*)d_in[4];
  const float* pw  = (const float*)d_in[5];
  const float* pb  = (const float*)d_in[6];
  const float* gw  = (const float*)d_in[7];
  const float* gb  = (const float*)d_in[8];
  const float* cw  = (const float*)d_in[9];
  const float* cb  = (const float*)d_in[10];
  const float* g2  = (const float*)d_in[11];
  const float* b2  = (const float*)d_in[12];

  float* out = (float*)d_out;
  float* gateout = out + (size_t)B_ * LM_ * C_;

  const size_t NHL = (size_t)B_ * LO_ * C_;   // 8388608
  ushort_t* hbuf   = (ushort_t*)d_ws;                    // fp16, 16 MB
  float*    pooled = (float*)(hbuf + NHL);               // fp32, 32 MB
  ushort_t* pwh    = (ushort_t*)(pooled + NHL);          // fp16, 0.5 MB
  float*    scores = (float*)(pwh + (size_t)C_ * C_);

  hipLaunchKernelGGL(k_conv,    dim3(B_ * LO_ / 8), dim3(512), 0, stream,
                     lat, g1, b1, dw, db, cw, cb, pw, pwh, hbuf, pooled, scores);
  hipLaunchKernelGGL(k_topk,    dim3(B_), dim3(1024), 0, stream, scores, lat, g2, b2, out);
  hipLaunchKernelGGL(k_gemmepi, dim3(B_ * LO_ / 64), dim3(512), 0, stream,
                     hbuf, pwh, pb, pooled, gw, gb, g2, b2, out, gateout);
}

// Round 13
// 97.494 us; speedup vs baseline: 1.0926x; 1.0612x over previous
//
#include <hip/hip_runtime.h>
#include <hip/hip_bf16.h>
#include <hip/hip_fp16.h>
#include <math.h>

#define B_ 8
#define L_ 4096
#define C_ 512
#define LO_ 2048   // L/2
#define SLOTS 8
#define LM_ 2056   // SLOTS + LO_

typedef _Float16 f16x8 __attribute__((ext_vector_type(8)));
typedef __attribute__((ext_vector_type(4))) float f32x4;
typedef unsigned short ushort_t;

__device__ __forceinline__ float waveReduceSum(float v){
  #pragma unroll
  for (int off = 32; off; off >>= 1) v += __shfl_xor(v, off);
  return v;
}
__device__ __forceinline__ unsigned short f2h(float f){
  __half h = __float2half(f);          // RNE
  return *reinterpret_cast<unsigned short*>(&h);
}
__device__ __forceinline__ float dot4(float4 a, float4 b){
  return a.x*b.x + a.y*b.y + a.z*b.z + a.w*b.w;
}
__device__ __forceinline__ float sum4(float4 a){ return a.x + a.y + a.z + a.w; }

#define GLOAD_LDS16(g, l) __builtin_amdgcn_global_load_lds( \
    (__attribute__((address_space(1))) void*)(g), \
    (__attribute__((address_space(3))) void*)(l), 16, 0, 0)

// ---------------- fused: [pw cast] + LN1 + carrier score + depthwise conv + GELU + pooled ----
// (R11-verbatim) h -> fp16, pooled -> fp32. 2048 blocks x 512 threads; 8 outputs/block.
__global__ __launch_bounds__(512) void k_conv(
    const float* __restrict__ lat, const float* __restrict__ g1, const float* __restrict__ b1,
    const float* __restrict__ dw, const float* __restrict__ db,
    const float* __restrict__ cw, const float* __restrict__ cbp,
    const float* __restrict__ pw, ushort_t* __restrict__ pwh,
    ushort_t* __restrict__ hbuf, float* __restrict__ pooled, float* __restrict__ scores)
{
  __shared__ float rows[17][C_];   // 34 KB
  __shared__ float stat[17][3];    // m, rstd, sd
  __shared__ float sc_[2];         // sgc, sbc
  int blk = blockIdx.x;            // b * 256 + chunk
  int b = blk >> 8;
  int chunk = blk & 255;
  int t0 = chunk * 8;
  int tid = threadIdx.x;
  int wv = tid >> 6, lane = tid & 63;
  int lbase = 16 * chunk - 1;      // in-batch row of r=0 (may be -1)

  if (blk < 256){
    int i = blk * 1024 + tid * 2;
    float2 v = *(const float2*)(pw + i);
    ushort2 o; o.x = f2h(v.x); o.y = f2h(v.y);
    *(ushort2*)(pwh + i) = o;
  }

  int c4 = lane * 4;
  float4 glo = *(const float4*)(g1 + c4);
  float4 ghi = *(const float4*)(g1 + 256 + c4);
  float4 wlo = *(const float4*)(cw + c4);
  float4 whi = *(const float4*)(cw + 256 + c4);
  float4 gclo, gchi;
  gclo.x = glo.x*wlo.x; gclo.y = glo.y*wlo.y; gclo.z = glo.z*wlo.z; gclo.w = glo.w*wlo.w;
  gchi.x = ghi.x*whi.x; gchi.y = ghi.y*whi.y; gchi.z = ghi.z*whi.z; gchi.w = ghi.w*whi.w;

  if (wv == 7){
    float4 blo = *(const float4*)(b1 + c4);
    float4 bhi = *(const float4*)(b1 + 256 + c4);
    float sgc = waveReduceSum(sum4(gclo) + sum4(gchi));
    float sbc = waveReduceSum(dot4(blo, wlo) + dot4(bhi, whi));
    if (lane == 0){ sc_[0] = sgc; sc_[1] = sbc; }
  }

  for (int r = wv; r < 17; r += 8){
    int l = lbase + r;
    float4 v0, v1;
    if (l >= 0){
      const float* xp = lat + ((size_t)(b * L_ + l)) * C_;
      v0 = *(const float4*)(xp + c4);
      v1 = *(const float4*)(xp + 256 + c4);
    } else {
      v0.x=0.f; v0.y=0.f; v0.z=0.f; v0.w=0.f;
      v1 = v0;
    }
    *(float4*)&rows[r][c4] = v0;
    *(float4*)&rows[r][256 + c4] = v1;
    float s1 = waveReduceSum(sum4(v0) + sum4(v1));
    float s2 = waveReduceSum(dot4(v0, v0) + dot4(v1, v1));
    float sd = waveReduceSum(dot4(v0, gclo) + dot4(v1, gchi));
    if (lane == 0){
      float m = s1 * (1.f / C_);
      float var = s2 * (1.f / C_) - m * m;
      stat[r][0] = m;
      stat[r][1] = rsqrtf(var + 1e-5f);
      stat[r][2] = sd;
    }
  }
  __syncthreads();

  if (tid >= 1 && tid <= 16){
    int r = tid;
    float sc = (stat[r][2] - stat[r][0] * sc_[0]) * stat[r][1] + sc_[1] + cbp[0];
    scores[b * L_ + lbase + r] = sc;
  }

  int th = tid >> 7;
  int cq = (tid & 127) * 4;
  float4 gq = *(const float4*)(g1 + cq);
  float4 bq = *(const float4*)(b1 + cq);
  float4 dbq = *(const float4*)(db + cq);
  float4 w0 = *(const float4*)(dw + cq*3);
  float4 w1 = *(const float4*)(dw + cq*3 + 4);
  float4 w2 = *(const float4*)(dw + cq*3 + 8);
  float wk[4][3] = {{w0.x, w0.y, w0.z}, {w0.w, w1.x, w1.y},
                    {w1.z, w1.w, w2.x}, {w2.y, w2.z, w2.w}};
  float gk[4] = {gq.x, gq.y, gq.z, gq.w};
  float bk[4] = {bq.x, bq.y, bq.z, bq.w};
  float dbk[4] = {dbq.x, dbq.y, dbq.z, dbq.w};
  #pragma unroll
  for (int i = 0; i < 2; i++){
    int t = th * 2 + i;
    int rl = 2*t, rm = 2*t+1, rrg = 2*t+2;
    float4 xl = *(const float4*)&rows[rl][cq];
    float4 xm = *(const float4*)&rows[rm][cq];
    float4 xrr = *(const float4*)&rows[rrg][cq];
    float ml = stat[rl][0], rlr = stat[rl][1];
    float mm = stat[rm][0], rmr = stat[rm][1];
    float mr2 = stat[rrg][0], rrr = stat[rrg][1];
    bool zpad = (chunk == 0 && t == 0);
    float xlv[4] = {xl.x, xl.y, xl.z, xl.w};
    float xmv[4] = {xm.x, xm.y, xm.z, xm.w};
    float xrv[4] = {xrr.x, xrr.y, xrr.z, xrr.w};
    ushort4 hv;
    float4 pv;
    unsigned short* hp = (unsigned short*)&hv;
    float* pp = (float*)&pv;
    #pragma unroll
    for (int k = 0; k < 4; k++){
      float n0 = zpad ? 0.f : ((xlv[k] - ml) * rlr * gk[k] + bk[k]);
      float n1 = (xmv[k] - mm) * rmr * gk[k] + bk[k];
      float n2 = (xrv[k] - mr2) * rrr * gk[k] + bk[k];
      float hh = n0 * wk[k][0] + n1 * wk[k][1] + n2 * wk[k][2] + dbk[k];
      float ge = 0.5f * hh * (1.f + erff(hh * 0.70710678118654752440f));
      hp[k] = f2h(ge);
      pp[k] = 0.5f * (xmv[k] + xrv[k]);
    }
    size_t oidx = ((size_t)(b * LO_ + t0 + t)) * C_ + cq;
    *(ushort4*)(hbuf + oidx) = hv;
    *(float4*)(pooled + oidx) = pv;
  }
}

// ============ fused GEMM + epilogue — R11 control flow; k-major unit layout (bank-conflict fix) =
// 256 blocks x 512 threads (8 waves). Block = 64 reduced rows x all 512 cols.
// Per-kt double-buffered global_load_lds staging (R11-verbatim schedule). LDS unit layout is
// k-chunk-major: chunk (row R, kchunk S) of a 16-row unit lives at unit*512 + S*128 + R*8.
// Both sides changed together (rule 21): stage source lane->(row=lane&15, S=lane>>4); frag read
// offset unit*512 + kq*16 + fr*8. Read-phase banks: 4*fr mod 32 -> ~2-way (was 8-way at 16*fr).
__global__ __launch_bounds__(512, 4) void k_gemmepi(
    const ushort_t* __restrict__ Ah, const ushort_t* __restrict__ Bw,
    const float* __restrict__ pb, const float* __restrict__ pooled,
    const float* __restrict__ gw, const float* __restrict__ gbp,
    const float* __restrict__ g2, const float* __restrict__ b2,
    float* __restrict__ out, float* __restrict__ gateout)
{
  __shared__ union UU {
    struct { ushort_t As[2][64*32]; ushort_t Bs[2][512*32]; } g;  // 8KB + 64KB = 72KB
    float red[16*516];                                            // 33KB chunk (reused after GEMM)
  } u;

  int blk = blockIdx.x;          // 0..255, 64 rows each; 32 blocks per batch (no crossing)
  int R0 = blk * 64;
  int tid = threadIdx.x;
  int w = tid >> 6, lane = tid & 63;
  const ushort_t* Ap = Ah + (size_t)R0 * C_;

#define STAGE(buf, kt) { \
    int kk = (kt) * 32; \
    if (w < 4){ \
      int ar = w*16 + (lane & 15); \
      GLOAD_LDS16(Ap + (size_t)ar*C_ + kk + (lane>>4)*8, &u.g.As[buf][w*16*32]); \
    } \
    _Pragma("unroll") \
    for (int uu = 0; uu < 4; uu++){ \
      int unit = w + uu*8; \
      int brow = unit*16 + (lane & 15); \
      GLOAD_LDS16(Bw + (size_t)brow*C_ + kk + (lane>>4)*8, &u.g.Bs[buf][unit*16*32]); \
    } }

  int fr = lane & 15, kq = (lane >> 4) * 8;
  int wc = w * 64;
  f32x4 acc[4][4];
  #pragma unroll
  for (int m = 0; m < 4; m++)
    #pragma unroll
    for (int n = 0; n < 4; n++)
      acc[m][n] = (f32x4){0.f, 0.f, 0.f, 0.f};

  STAGE(0, 0);
  __syncthreads();
  for (int kt = 0; kt < 16; kt++){
    int cur = kt & 1;
    if (kt < 15){ STAGE(cur ^ 1, kt + 1); }
    f16x8 af[4], bfr[4];
    #pragma unroll
    for (int m = 0; m < 4; m++)
      af[m] = *(const f16x8*)&u.g.As[cur][m*512 + kq*16 + fr*8];
    #pragma unroll
    for (int n = 0; n < 4; n++)
      bfr[n] = *(const f16x8*)&u.g.Bs[cur][(wc + n*16)*32 + kq*16 + fr*8];
    #pragma unroll
    for (int m = 0; m < 4; m++)
      #pragma unroll
      for (int n = 0; n < 4; n++)
        acc[m][n] = __builtin_amdgcn_mfma_f32_16x16x32_f16(af[m], bfr[n], acc[m][n], 0, 0, 0);
    __syncthreads();   // drains staging (vmcnt0) + protects buffer reuse
  }
#undef STAGE

  // bias add (C/D layout: col = lane&15, row = (lane>>4)*4 + j)
  int cq = fr, rq = (lane >> 4) * 4;
  #pragma unroll
  for (int n = 0; n < 4; n++){
    float pbv = pb[wc + n*16 + cq];
    #pragma unroll
    for (int m = 0; m < 4; m++)
      #pragma unroll
      for (int j = 0; j < 4; j++)
        acc[m][n][j] += pbv;
  }

  // epilogue params
  int c4 = lane * 4;
  float4 gw1lo = *(const float4*)(gw + c4);
  float4 gw1hi = *(const float4*)(gw + 256 + c4);
  float4 gw2lo = *(const float4*)(gw + C_ + c4);
  float4 gw2hi = *(const float4*)(gw + C_ + 256 + c4);
  float4 g2lo = *(const float4*)(g2 + c4);
  float4 g2hi = *(const float4*)(g2 + 256 + c4);
  float4 b2lo = *(const float4*)(b2 + c4);
  float4 b2hi = *(const float4*)(b2 + 256 + c4);
  float gb0 = gbp[0];

  // 4 chunks of 16 rows: flush acc[g] -> red LDS, then row-waves finish
  #pragma unroll
  for (int g = 0; g < 4; g++){
    #pragma unroll
    for (int n = 0; n < 4; n++)
      #pragma unroll
      for (int j = 0; j < 4; j++)
        u.red[(rq + j)*516 + wc + n*16 + cq] = acc[g][n][j];
    __syncthreads();
    // wave w -> rows w*2, w*2+1 of this chunk
    #pragma unroll
    for (int rr = 0; rr < 2; rr++){
      int rloc = w*2 + rr;
      int grow = R0 + g*16 + rloc;           // global reduced row (= b*LO + l)
      const float* redrow = &u.red[rloc * 516];
      float4 rlo = *(const float4*)&redrow[c4];
      float4 rhi = *(const float4*)&redrow[256 + c4];
      const float* prow = pooled + (size_t)grow * C_;
      float4 plov = *(const float4*)(prow + c4);
      float4 phiv = *(const float4*)(prow + 256 + c4);
      float rdot = waveReduceSum(dot4(rlo, gw1lo) + dot4(rhi, gw1hi));
      float pdot = waveReduceSum(dot4(plov, gw2lo) + dot4(phiv, gw2hi));
      float gate = 0.5f + 0.5f / (1.f + expf(-(rdot + pdot + gb0)));
      float4 mlo, mhi;
      mlo.x = plov.x + gate * (rlo.x - plov.x);
      mlo.y = plov.y + gate * (rlo.y - plov.y);
      mlo.z = plov.z + gate * (rlo.z - plov.z);
      mlo.w = plov.w + gate * (rlo.w - plov.w);
      mhi.x = phiv.x + gate * (rhi.x - phiv.x);
      mhi.y = phiv.y + gate * (rhi.y - phiv.y);
      mhi.z = phiv.z + gate * (rhi.z - phiv.z);
      mhi.w = phiv.w + gate * (rhi.w - phiv.w);
      float s1 = waveReduceSum(sum4(mlo) + sum4(mhi));
      float s2 = waveReduceSum(dot4(mlo, mlo) + dot4(mhi, mhi));
      float mean = s1 * (1.f / C_);
      float rstd = rsqrtf(s2 * (1.f / C_) - mean * mean + 1e-5f);
      int b = grow >> 11, l = grow & (LO_ - 1);
      float* op = out + ((size_t)(b * LM_ + SLOTS + l)) * C_;
      float4 olo, ohi;
      olo.x = (mlo.x - mean) * rstd * g2lo.x + b2lo.x;
      olo.y = (mlo.y - mean) * rstd * g2lo.y + b2lo.y;
      olo.z = (mlo.z - mean) * rstd * g2lo.z + b2lo.z;
      olo.w = (mlo.w - mean) * rstd * g2lo.w + b2lo.w;
      ohi.x = (mhi.x - mean) * rstd * g2hi.x + b2hi.x;
      ohi.y = (mhi.y - mean) * rstd * g2hi.y + b2hi.y;
      ohi.z = (mhi.z - mean) * rstd * g2hi.z + b2hi.z;
      ohi.w = (mhi.w - mean) * rstd * g2hi.w + b2hi.w;
      *(float4*)(op + c4) = olo;
      *(float4*)(op + 256 + c4) = ohi;
      if (lane == 0) gateout[grow] = gate;
    }
    __syncthreads();   // chunk buffer reuse
  }
}

// ---------------- top-8 (block per batch) + carrier gather + LN2 (R11-verbatim) ----------------
__global__ __launch_bounds__(1024) void k_topk(
    const float* __restrict__ scores, const float* __restrict__ lat,
    const float* __restrict__ g2, const float* __restrict__ b2, float* __restrict__ out)
{
  __shared__ float sv[L_];
  __shared__ float rv_[16];
  __shared__ int   ri_[16];
  __shared__ int   chosen[SLOTS];
  int b = blockIdx.x, tid = threadIdx.x;
  #pragma unroll
  for (int j = 0; j < 4; j++) sv[tid + j * 1024] = scores[b * L_ + tid + j * 1024];
  __syncthreads();
  int wv = tid >> 6, lane = tid & 63;
  for (int it = 0; it < SLOTS; it++){
    float best = -INFINITY; int bi = L_;
    #pragma unroll
    for (int j = 0; j < 4; j++){
      int i = tid + j * 1024;
      float v = sv[i];
      if (v > best || (v == best && i < bi)){ best = v; bi = i; }
    }
    #pragma unroll
    for (int off = 32; off; off >>= 1){
      float ov = __shfl_xor(best, off); int oi = __shfl_xor(bi, off);
      if (ov > best || (ov == best && oi < bi)){ best = ov; bi = oi; }
    }
    if (lane == 0){ rv_[wv] = best; ri_[wv] = bi; }
    __syncthreads();
    if (tid == 0){
      for (int w2 = 1; w2 < 16; w2++){
        if (rv_[w2] > best || (rv_[w2] == best && ri_[w2] < bi)){ best = rv_[w2]; bi = ri_[w2]; }
      }
      chosen[it] = bi;
      sv[bi] = -INFINITY;
    }
    __syncthreads();
  }
  if (tid == 0){
    for (int i = 0; i < SLOTS; i++)
      for (int j = i + 1; j < SLOTS; j++)
        if (chosen[j] < chosen[i]){ int t = chosen[i]; chosen[i] = chosen[j]; chosen[j] = t; }
  }
  __syncthreads();
  if (wv < SLOTS){
    int s = wv;
    int l = chosen[s];
    const float* x = lat + ((size_t)(b * L_ + l)) * C_;
    float xs[8];
    float s1 = 0.f, s2 = 0.f;
    #pragma unroll
    for (int i = 0; i < 2; i++){
      float4 vv = *(const float4*)(x + i * 256 + lane * 4);
      xs[i*4+0] = vv.x; xs[i*4+1] = vv.y; xs[i*4+2] = vv.z; xs[i*4+3] = vv.w;
      s1 += vv.x + vv.y + vv.z + vv.w;
      s2 += vv.x*vv.x + vv.y*vv.y + vv.z*vv.z + vv.w*vv.w;
    }
    s1 = waveReduceSum(s1); s2 = waveReduceSum(s2);
    float m = s1 * (1.f / C_);
    float rstd = rsqrtf(s2 * (1.f / C_) - m * m + 1e-5f);
    float* o = out + ((size_t)(b * LM_ + s)) * C_;
    #pragma unroll
    for (int i = 0; i < 2; i++){
      int cc = i * 256 + lane * 4;
      float4 gv = *(const float4*)(g2 + cc);
      float4 bv = *(const float4*)(b2 + cc);
      float4 ov;
      ov.x = (xs[i*4+0] - m) * rstd * gv.x + bv.x;
      ov.y = (xs[i*4+1] - m) * rstd * gv.y + bv.y;
      ov.z = (xs[i*4+2] - m) * rstd * gv.z + bv.z;
      ov.w = (xs[i*4+3] - m) * rstd * gv.w + bv.w;
      *(float4*)(o + cc) = ov;
    }
  }
}

extern "C" void kernel_launch(void* const* d_in, const int* in_sizes, int n_in,
                              void* d_out, int out_size, void* d_ws, size_t ws_size,
                              hipStream_t stream)
{
  const float* lat = (const float*)d_in[0];
  const float* g1  = (const float*)d_in[1];
  const float* b1  = (const float*)d_in[2];
  const float* dw  = (const float*)d_in[3];
  const float* db  = (const float*)d_in[4];
  const float* pw  = (const float*)d_in[5];
  const float* pb  = (const float*)d_in[6];
  const float* gw  = (const float*)d_in[7];
  const float* gb  = (const float*)d_in[8];
  const float* cw  = (const float*)d_in[9];
  const float* cb  = (const float*)d_in[10];
  const float* g2  = (const float*)d_in[11];
  const float* b2  = (const float*)d_in[12];

  float* out = (float*)d_out;
  float* gateout = out + (size_t)B_ * LM_ * C_;

  const size_t NHL = (size_t)B_ * LO_ * C_;   // 8388608
  ushort_t* hbuf   = (ushort_t*)d_ws;                    // fp16, 16 MB
  float*    pooled = (float*)(hbuf + NHL);               // fp32, 32 MB
  ushort_t* pwh    = (ushort_t*)(pooled + NHL);          // fp16, 0.5 MB
  float*    scores = (float*)(pwh + (size_t)C_ * C_);

  hipLaunchKernelGGL(k_conv,    dim3(B_ * LO_ / 8), dim3(512), 0, stream,
                     lat, g1, b1, dw, db, cw, cb, pw, pwh, hbuf, pooled, scores);
  hipLaunchKernelGGL(k_topk,    dim3(B_), dim3(1024), 0, stream, scores, lat, g2, b2, out);
  hipLaunchKernelGGL(k_gemmepi, dim3(B_ * LO_ / 64), dim3(512), 0, stream,
                     hbuf, pwh, pb, pooled, gw, gb, g2, b2, out, gateout);
}